// Round 4
// baseline (1267.573 us; speedup 1.0000x reference)
//
#include <hip/hip_runtime.h>
#include <hip/hip_bf16.h>
#include <math.h>

#define NBATCH 4
#define NSEQ   1024
#define RD     256
#define NHEAD  8
#define HD     64
#define NHD    512   // NHEAD*HD

// ---------------------------------------------------------------------------
// Mask normalization (robust to bool-byte vs int32 upload; see R2 notes).
// ---------------------------------------------------------------------------
__global__ __launch_bounds__(1024) void mask_norm(
    const void* __restrict__ mraw, unsigned char* __restrict__ nm)
{
    __shared__ int isByteLayout;
    const int t = threadIdx.x;                  // 0..1023
    if (t == 0) isByteLayout = 0;
    __syncthreads();
    const int* mi = (const int*)mraw;
    int v = mi[t];                              // first 4096 bytes either way
    if (v & ~1) isByteLayout = 1;               // benign race, all write 1
    __syncthreads();
    const unsigned char* mb = (const unsigned char*)mraw;
    if (isByteLayout) {
        #pragma unroll
        for (int j = 0; j < 4; j++) { int k = t*4 + j; nm[k] = mb[k] ? 1 : 0; }
    } else {
        #pragma unroll
        for (int j = 0; j < 4; j++) { int k = t*4 + j; nm[k] = mi[k] ? 1 : 0; }
    }
}

// ---------------------------------------------------------------------------
// Complex projection: Y = X @ (Wr + i Wi)^T, X:(4096,256) cplx fp32, W:(512,256)
// Output remapped to (B, NH, NSEQ, 64) real/imag planes, stored bf16.
// ---------------------------------------------------------------------------
__global__ __launch_bounds__(256) void cproj_qkv(
    const float* __restrict__ Xr, const float* __restrict__ Xi,
    const float* __restrict__ Wr, const float* __restrict__ Wi,
    __hip_bfloat16* __restrict__ Yr, __hip_bfloat16* __restrict__ Yi)
{
    __shared__ float sXr[64][33], sXi[64][33], sWr[64][33], sWi[64][33];
    const int tid = threadIdx.x;
    const int tx = tid & 15, ty = tid >> 4;
    const int row0 = blockIdx.y * 64, col0 = blockIdx.x * 64;
    float ar[4][4] = {{0.f}}, ai[4][4] = {{0.f}};

    for (int k0 = 0; k0 < RD; k0 += 32) {
        __syncthreads();
        #pragma unroll
        for (int j = 0; j < 8; j++) {
            int idx = j*256 + tid;
            int r = idx >> 5, c = idx & 31;
            sXr[r][c] = Xr[(size_t)(row0 + r)*RD + k0 + c];
            sXi[r][c] = Xi[(size_t)(row0 + r)*RD + k0 + c];
            sWr[r][c] = Wr[(size_t)(col0 + r)*RD + k0 + c];
            sWi[r][c] = Wi[(size_t)(col0 + r)*RD + k0 + c];
        }
        __syncthreads();
        #pragma unroll 8
        for (int k = 0; k < 32; k++) {
            float xr[4], xi[4], wr[4], wi[4];
            #pragma unroll
            for (int i = 0; i < 4; i++) {
                xr[i] = sXr[ty + 16*i][k];  xi[i] = sXi[ty + 16*i][k];
                wr[i] = sWr[tx + 16*i][k];  wi[i] = sWi[tx + 16*i][k];
            }
            #pragma unroll
            for (int i = 0; i < 4; i++)
                #pragma unroll
                for (int j = 0; j < 4; j++) {
                    ar[i][j] = fmaf(xr[i], wr[j], fmaf(-xi[i], wi[j], ar[i][j]));
                    ai[i][j] = fmaf(xr[i], wi[j], fmaf( xi[i], wr[j], ai[i][j]));
                }
        }
    }
    #pragma unroll
    for (int i = 0; i < 4; i++)
        #pragma unroll
        for (int j = 0; j < 4; j++) {
            int row = row0 + ty + 16*i;      // m = b*1024 + n
            int col = col0 + tx + 16*j;      // c = h*64 + d
            int b = row >> 10, n = row & 1023;
            int h = col >> 6,  d = col & 63;
            size_t o = (((size_t)(b*NHEAD + h))*NSEQ + n)*HD + d;
            Yr[o] = __float2bfloat16(ar[i][j]);
            Yi[o] = __float2bfloat16(ai[i][j]);
        }
}

// ---------------------------------------------------------------------------
// Output projection: Out = A @ (WOr + i WOi)^T, A:(4096,512) cplx bf16,
// WO:(256,512) fp32.
// Layout adaptive: out_size==1M -> real part only (harness casts complex ref
// to float32); out_size>=2M -> planar [real plane | imag plane].
// ---------------------------------------------------------------------------
__global__ __launch_bounds__(256) void cproj_out(
    const __hip_bfloat16* __restrict__ Xr, const __hip_bfloat16* __restrict__ Xi,
    const float* __restrict__ Wr, const float* __restrict__ Wi,
    float* __restrict__ Out, int writeImagPlane)
{
    __shared__ float sXr[64][33], sXi[64][33], sWr[64][33], sWi[64][33];
    const int tid = threadIdx.x;
    const int tx = tid & 15, ty = tid >> 4;
    const int row0 = blockIdx.y * 64, col0 = blockIdx.x * 64;
    float ar[4][4] = {{0.f}}, ai[4][4] = {{0.f}};

    for (int k0 = 0; k0 < NHD; k0 += 32) {
        __syncthreads();
        #pragma unroll
        for (int j = 0; j < 8; j++) {
            int idx = j*256 + tid;
            int r = idx >> 5, c = idx & 31;
            sXr[r][c] = __bfloat162float(Xr[(size_t)(row0 + r)*NHD + k0 + c]);
            sXi[r][c] = __bfloat162float(Xi[(size_t)(row0 + r)*NHD + k0 + c]);
            sWr[r][c] = Wr[(size_t)(col0 + r)*NHD + k0 + c];
            sWi[r][c] = Wi[(size_t)(col0 + r)*NHD + k0 + c];
        }
        __syncthreads();
        #pragma unroll 8
        for (int k = 0; k < 32; k++) {
            float xr[4], xi[4], wr[4], wi[4];
            #pragma unroll
            for (int i = 0; i < 4; i++) {
                xr[i] = sXr[ty + 16*i][k];  xi[i] = sXi[ty + 16*i][k];
                wr[i] = sWr[tx + 16*i][k];  wi[i] = sWi[tx + 16*i][k];
            }
            #pragma unroll
            for (int i = 0; i < 4; i++)
                #pragma unroll
                for (int j = 0; j < 4; j++) {
                    ar[i][j] = fmaf(xr[i], wr[j], fmaf(-xi[i], wi[j], ar[i][j]));
                    ai[i][j] = fmaf(xr[i], wi[j], fmaf( xi[i], wr[j], ai[i][j]));
                }
        }
    }
    const size_t TOT = (size_t)NBATCH * NSEQ * RD;   // 1,048,576
    #pragma unroll
    for (int i = 0; i < 4; i++)
        #pragma unroll
        for (int j = 0; j < 4; j++) {
            int row = row0 + ty + 16*i;
            int col = col0 + tx + 16*j;
            size_t o = (size_t)row*RD + col;
            Out[o] = ar[i][j];
            if (writeImagPlane) Out[o + TOT] = ai[i][j];
        }
}

// ---------------------------------------------------------------------------
// Fused attention per (b,h): scores = |Qp conj(Kp)^T|/8, masked softmax, @ Vp.
// ---------------------------------------------------------------------------
__global__ __launch_bounds__(256) void attn_fused(
    const __hip_bfloat16* __restrict__ Qr, const __hip_bfloat16* __restrict__ Qi,
    const __hip_bfloat16* __restrict__ Kr, const __hip_bfloat16* __restrict__ Ki,
    const __hip_bfloat16* __restrict__ Vr, const __hip_bfloat16* __restrict__ Vi,
    const unsigned char* __restrict__ mask,
    __hip_bfloat16* __restrict__ Ar, __hip_bfloat16* __restrict__ Ai)
{
    __shared__ float sQr[8][64], sQi[8][64];
    __shared__ float sTr[64][65], sTi[64][65];      // K transposed / V tiles
    __shared__ __hip_bfloat16 sW[8][1024];          // softmax weights

    const int tid  = threadIdx.x;
    const int lane = tid & 63;
    const int wave = tid >> 6;
    const int qt   = blockIdx.x & 127;              // NQ/8 = 128 tiles
    const int bh   = blockIdx.x >> 7;               // 0..31
    const int b    = bh >> 3;
    const int h    = bh & 7;
    const int lq   = wave * 2;                      // local q row (0..7)
    const int q0   = qt*8 + lq;

    const size_t kvbase = (size_t)bh * NSEQ * HD;   // Nq == Nk

    // stage 8 Q rows
    #pragma unroll
    for (int j = 0; j < 2; j++) {
        int idx = j*256 + tid;
        int r = idx >> 6, d = idx & 63;
        sQr[r][d] = __bfloat162float(Qr[kvbase + (size_t)(qt*8 + r)*HD + d]);
        sQi[r][d] = __bfloat162float(Qi[kvbase + (size_t)(qt*8 + r)*HD + d]);
    }

    float sc0[16], sc1[16];
    const int mbase = b * NSEQ;

    // ---- scores: s = Qp . conj(Kp), |s|/8, mask ----
    for (int t = 0; t < 16; t++) {
        const int k0 = t*64;
        __syncthreads();
        #pragma unroll
        for (int j = 0; j < 16; j++) {
            int idx = j*256 + tid;
            int key = idx >> 6, d = idx & 63;
            sTr[d][key] = __bfloat162float(Kr[kvbase + (size_t)(k0 + key)*HD + d]);
            sTi[d][key] = __bfloat162float(Ki[kvbase + (size_t)(k0 + key)*HD + d]);
        }
        __syncthreads();
        float a0 = 0.f, c0 = 0.f, a1 = 0.f, c1 = 0.f;
        #pragma unroll 8
        for (int d = 0; d < 64; d++) {
            float kr  = sTr[d][lane], ki = sTi[d][lane];
            float q0r = sQr[lq][d],   q0i = sQi[lq][d];
            float q1r = sQr[lq+1][d], q1i = sQi[lq+1][d];
            a0 = fmaf(q0r, kr, fmaf( q0i, ki, a0));   // real part (conj K)
            c0 = fmaf(q0i, kr, fmaf(-q0r, ki, c0));   // imag part
            a1 = fmaf(q1r, kr, fmaf( q1i, ki, a1));
            c1 = fmaf(q1i, kr, fmaf(-q1r, ki, c1));
        }
        bool mv = mask[mbase + k0 + lane] != 0;
        sc0[t] = mv ? 0.125f * sqrtf(a0*a0 + c0*c0) : -INFINITY;
        sc1[t] = mv ? 0.125f * sqrtf(a1*a1 + c1*c1) : -INFINITY;
    }

    // ---- softmax over 1024 keys (16 regs x 64 lanes) ----
    float m0 = -INFINITY, m1 = -INFINITY;
    #pragma unroll
    for (int t = 0; t < 16; t++) { m0 = fmaxf(m0, sc0[t]); m1 = fmaxf(m1, sc1[t]); }
    #pragma unroll
    for (int off = 32; off >= 1; off >>= 1) {
        m0 = fmaxf(m0, __shfl_xor(m0, off, 64));
        m1 = fmaxf(m1, __shfl_xor(m1, off, 64));
    }
    float s0 = 0.f, s1 = 0.f;
    #pragma unroll
    for (int t = 0; t < 16; t++) {
        float e0 = (sc0[t] == -INFINITY) ? 0.f : __expf(sc0[t] - m0);
        float e1 = (sc1[t] == -INFINITY) ? 0.f : __expf(sc1[t] - m1);
        sc0[t] = e0; sc1[t] = e1;
        s0 += e0; s1 += e1;
    }
    #pragma unroll
    for (int off = 32; off >= 1; off >>= 1) {
        s0 += __shfl_xor(s0, off, 64);
        s1 += __shfl_xor(s1, off, 64);
    }
    float inv0 = (s0 > 0.f) ? 1.f/s0 : 0.f;
    float inv1 = (s1 > 0.f) ? 1.f/s1 : 0.f;
    #pragma unroll
    for (int t = 0; t < 16; t++) {
        sW[lq][t*64 + lane]   = __float2bfloat16(sc0[t]*inv0);
        sW[lq+1][t*64 + lane] = __float2bfloat16(sc1[t]*inv1);
    }

    // ---- PV: attn = w @ Vp ----
    float or0 = 0.f, oi0 = 0.f, or1 = 0.f, oi1 = 0.f;
    for (int t = 0; t < 16; t++) {
        const int k0 = t*64;
        __syncthreads();
        #pragma unroll
        for (int j = 0; j < 16; j++) {
            int idx = j*256 + tid;
            int key = idx >> 6, d = idx & 63;
            sTr[key][d] = __bfloat162float(Vr[kvbase + (size_t)(k0 + key)*HD + d]);
            sTi[key][d] = __bfloat162float(Vi[kvbase + (size_t)(k0 + key)*HD + d]);
        }
        __syncthreads();
        #pragma unroll 8
        for (int kk = 0; kk < 64; kk++) {
            float w0 = __bfloat162float(sW[lq][k0+kk]);
            float w1 = __bfloat162float(sW[lq+1][k0+kk]);
            float vr = sTr[kk][lane], vi = sTi[kk][lane];
            or0 = fmaf(w0, vr, or0);  oi0 = fmaf(w0, vi, oi0);
            or1 = fmaf(w1, vr, or1);  oi1 = fmaf(w1, vi, oi1);
        }
    }

    // attn layout for out-proj: (B*NSEQ, NHD)
    size_t o = ((size_t)(b*NSEQ + q0))*NHD + h*HD + lane;
    Ar[o]       = __float2bfloat16(or0);  Ai[o]       = __float2bfloat16(oi0);
    Ar[o + NHD] = __float2bfloat16(or1);  Ai[o + NHD] = __float2bfloat16(oi1);
}

// ---------------------------------------------------------------------------
extern "C" void kernel_launch(void* const* d_in, const int* in_sizes, int n_in,
                              void* d_out, int out_size, void* d_ws, size_t ws_size,
                              hipStream_t stream)
{
    const float* Qr  = (const float*)d_in[0];
    const float* Qi  = (const float*)d_in[1];
    const float* Kr  = (const float*)d_in[2];
    const float* Ki  = (const float*)d_in[3];
    const float* Vr  = (const float*)d_in[4];
    const float* Vi  = (const float*)d_in[5];
    const float* WQr = (const float*)d_in[6];
    const float* WQi = (const float*)d_in[7];
    const float* WKr = (const float*)d_in[8];
    const float* WKi = (const float*)d_in[9];
    const float* WVr = (const float*)d_in[10];
    const float* WVi = (const float*)d_in[11];
    const float* WOr = (const float*)d_in[12];
    const float* WOi = (const float*)d_in[13];
    float* out = (float*)d_out;

    const size_t P = (size_t)NBATCH * NHEAD * NSEQ * HD;   // 2,097,152 elems
    __hip_bfloat16* bws = (__hip_bfloat16*)d_ws;           // 8 planes * 4MB = 32MB
    __hip_bfloat16* Qpr = bws + 0*P;  __hip_bfloat16* Qpi = bws + 1*P;
    __hip_bfloat16* Kpr = bws + 2*P;  __hip_bfloat16* Kpi = bws + 3*P;
    __hip_bfloat16* Vpr = bws + 4*P;  __hip_bfloat16* Vpi = bws + 5*P;
    __hip_bfloat16* Apr = bws + 6*P;  __hip_bfloat16* Api = bws + 7*P;
    unsigned char* nmask = (unsigned char*)(bws + 8*P);    // 4096 bytes

    const size_t TOT = (size_t)NBATCH * NSEQ * RD;          // 1,048,576
    const int writeImagPlane = ((size_t)out_size >= 2*TOT) ? 1 : 0;

    mask_norm<<<1, 1024, 0, stream>>>(d_in[14], nmask);
    cproj_qkv<<<dim3(8, 64), 256, 0, stream>>>(Qr, Qi, WQr, WQi, Qpr, Qpi);
    cproj_qkv<<<dim3(8, 64), 256, 0, stream>>>(Kr, Ki, WKr, WKi, Kpr, Kpi);
    cproj_qkv<<<dim3(8, 64), 256, 0, stream>>>(Vr, Vi, WVr, WVi, Vpr, Vpi);
    attn_fused<<<dim3(4096), 256, 0, stream>>>(Qpr, Qpi, Kpr, Kpi, Vpr, Vpi,
                                               nmask, Apr, Api);
    cproj_out<<<dim3(4, 64), 256, 0, stream>>>(Apr, Api, WOr, WOi, out,
                                               writeImagPlane);
}

// Round 5
// 273.842 us; speedup vs baseline: 4.6288x; 4.6288x over previous
//
#include <hip/hip_runtime.h>
#include <math.h>

#define NBATCH 4
#define NSEQ   1024
#define RD     256
#define NHEAD  8
#define HD     64
#define NHD    512   // NHEAD*HD

typedef __attribute__((ext_vector_type(8))) short  short8;
typedef __attribute__((ext_vector_type(4))) short  short4v;
typedef __attribute__((ext_vector_type(4))) float  float4v;

#define MFMA16(a,b,c) __builtin_amdgcn_mfma_f32_16x16x32_bf16(a,b,c,0,0,0)

static __device__ __forceinline__ unsigned short f2b(float f) {
    union { float f; unsigned u; } x; x.f = f;
    unsigned r = x.u + 0x7fffu + ((x.u >> 16) & 1u);   // RNE; inputs finite
    return (unsigned short)(r >> 16);
}
static __device__ __forceinline__ void st4(short* dst, float4v v) {
    short4v p;
    p[0] = (short)f2b(v[0]); p[1] = (short)f2b(v[1]);
    p[2] = (short)f2b(v[2]); p[3] = (short)f2b(v[3]);
    *(short4v*)dst = p;
}

// ---------------------------------------------------------------------------
// Mask normalization (layout-adaptive; validated in R4).
// ---------------------------------------------------------------------------
__global__ __launch_bounds__(1024) void mask_norm(
    const void* __restrict__ mraw, unsigned char* __restrict__ nm)
{
    __shared__ int isByteLayout;
    const int t = threadIdx.x;
    if (t == 0) isByteLayout = 0;
    __syncthreads();
    const int* mi = (const int*)mraw;
    int v = mi[t];
    if (v & ~1) isByteLayout = 1;
    __syncthreads();
    const unsigned char* mb = (const unsigned char*)mraw;
    if (isByteLayout) {
        #pragma unroll
        for (int j = 0; j < 4; j++) { int k = t*4 + j; nm[k] = mb[k] ? 1 : 0; }
    } else {
        #pragma unroll
        for (int j = 0; j < 4; j++) { int k = t*4 + j; nm[k] = mi[k] ? 1 : 0; }
    }
}

// ---------------------------------------------------------------------------
// Complex projection via MFMA: Y = X @ (Wr + i Wi)^T
// X:(4096,RD) fp32 planes, W:(512,RD) fp32. Y planes bf16.
// transposeOut=0: Y[bh][n][d]; =1: Y[bh][d][n] (for V, so PV B-frags stage
// with straight vector copies).
// 64x64 tile, 4 waves x 16-row strips, K-chunks of 64.
// ---------------------------------------------------------------------------
__global__ __launch_bounds__(256) void cgemm_proj(
    const float* __restrict__ X_r, const float* __restrict__ X_i,
    const float* __restrict__ W_r, const float* __restrict__ W_i,
    short* __restrict__ Y_r, short* __restrict__ Y_i, int transposeOut)
{
    __shared__ short sX[2][64][72];
    __shared__ short sW[3][64][72];   // Wr, Wi, -Wi
    const int tid  = threadIdx.x;
    const int lane = tid & 63, wave = tid >> 6;
    const int quad = lane >> 4, l16 = lane & 15;
    const int n0 = blockIdx.x * 64, m0 = blockIdx.y * 64;

    float4v zf = {0.f,0.f,0.f,0.f};
    float4v Yr[4], Yi[4];
    #pragma unroll
    for (int t = 0; t < 4; t++) { Yr[t] = zf; Yi[t] = zf; }

    for (int kc = 0; kc < RD; kc += 64) {
        __syncthreads();
        #pragma unroll
        for (int i = 0; i < 4; i++) {
            int gi = i*256 + tid, row = gi >> 4, col = (gi & 15)*4;
            float4v xr = *(const float4v*)&X_r[(size_t)(m0+row)*RD + kc + col];
            float4v xi = *(const float4v*)&X_i[(size_t)(m0+row)*RD + kc + col];
            st4(&sX[0][row][col], xr);
            st4(&sX[1][row][col], xi);
            float4v wr = *(const float4v*)&W_r[(size_t)(n0+row)*RD + kc + col];
            float4v wi = *(const float4v*)&W_i[(size_t)(n0+row)*RD + kc + col];
            st4(&sW[0][row][col], wr);
            st4(&sW[1][row][col], wi);
            float4v win = {-wi[0], -wi[1], -wi[2], -wi[3]};
            st4(&sW[2][row][col], win);
        }
        __syncthreads();
        short8 fxr[2], fxi[2];
        #pragma unroll
        for (int ds = 0; ds < 2; ds++) {
            fxr[ds] = *(short8*)&sX[0][wave*16 + l16][ds*32 + quad*8];
            fxi[ds] = *(short8*)&sX[1][wave*16 + l16][ds*32 + quad*8];
        }
        #pragma unroll
        for (int t = 0; t < 4; t++)
            #pragma unroll
            for (int ds = 0; ds < 2; ds++) {
                short8 wr  = *(short8*)&sW[0][t*16 + l16][ds*32 + quad*8];
                short8 wi  = *(short8*)&sW[1][t*16 + l16][ds*32 + quad*8];
                short8 win = *(short8*)&sW[2][t*16 + l16][ds*32 + quad*8];
                Yr[t] = MFMA16(fxr[ds], wr,  Yr[t]);
                Yr[t] = MFMA16(fxi[ds], win, Yr[t]);
                Yi[t] = MFMA16(fxr[ds], wi,  Yi[t]);
                Yi[t] = MFMA16(fxi[ds], wr,  Yi[t]);
            }
    }
    #pragma unroll
    for (int t = 0; t < 4; t++)
        #pragma unroll
        for (int r = 0; r < 4; r++) {
            int row = m0 + wave*16 + quad*4 + r;   // 0..4095: b*1024+n
            int col = n0 + t*16 + l16;             // 0..511:  h*64+d
            int b = row >> 10, n = row & 1023;
            int h = col >> 6,  d = col & 63;
            size_t o = transposeOut
                ? (((size_t)(b*NHEAD + h))*HD + d)*NSEQ + n
                : (((size_t)(b*NHEAD + h))*NSEQ + n)*HD + d;
            Y_r[o] = (short)f2b(Yr[t][r]);
            Y_i[o] = (short)f2b(Yi[t][r]);
        }
}

// ---------------------------------------------------------------------------
// Flash-style complex attention with MFMA.
// Block = 4 waves, 64 q rows per block, grid = 32 bh * 16 qtiles = 512.
// Q,K planes [bh][n][d] bf16; V planes [bh][d][n] bf16 (pre-transposed).
// ---------------------------------------------------------------------------
__global__ __launch_bounds__(256) void attn_mfma(
    const short* __restrict__ Qp_r, const short* __restrict__ Qp_i,
    const short* __restrict__ Kp_r, const short* __restrict__ Kp_i,
    const short* __restrict__ Vp_r, const short* __restrict__ Vp_i,
    const unsigned char* __restrict__ mask,
    short* __restrict__ Ar, short* __restrict__ Ai)
{
    __shared__ short sQ[3][64][72];       // Qr, Qi, -Qr
    __shared__ short sK[2][64][72];       // Kr, Ki  [key][d]
    __shared__ short sV[2][64][72];       // Vr, Vi  [d][key]
    __shared__ short sP[4][16][72];       // per-wave P strips
    __shared__ unsigned char smask[1024];

    const int tid  = threadIdx.x;
    const int lane = tid & 63, wave = tid >> 6;
    const int quad = lane >> 4, l16 = lane & 15;
    const int qt = blockIdx.x & 15;
    const int bh = blockIdx.x >> 4;
    const int b  = bh >> 3, h = bh & 7;
    const size_t base = (size_t)bh * (NSEQ*HD);

    ((int*)smask)[tid] = ((const int*)(mask + b*NSEQ))[tid];

    {   // stage 64 Q rows (+ negated real for conj arithmetic)
        const int q0 = qt*64;
        const short nk = (short)0x8000;
        short8 neg = {nk,nk,nk,nk,nk,nk,nk,nk};
        #pragma unroll
        for (int i = 0; i < 2; i++) {
            int gi = i*256 + tid, row = gi >> 3, col = (gi & 7)*8;
            short8 vr = *(const short8*)&Qp_r[base + (size_t)(q0+row)*HD + col];
            short8 vi = *(const short8*)&Qp_i[base + (size_t)(q0+row)*HD + col];
            *(short8*)&sQ[0][row][col] = vr;
            *(short8*)&sQ[1][row][col] = vi;
            *(short8*)&sQ[2][row][col] = vr ^ neg;
        }
    }

    float4v zf = {0.f,0.f,0.f,0.f};
    float4v Or[4], Oi[4];
    float mrow[4], lrow[4];
    #pragma unroll
    for (int t = 0; t < 4; t++) { Or[t] = zf; Oi[t] = zf; }
    #pragma unroll
    for (int r = 0; r < 4; r++) { mrow[r] = -1e30f; lrow[r] = 0.f; }

    for (int kt = 0; kt < 16; kt++) {
        const int k0 = kt*64;
        __syncthreads();
        #pragma unroll
        for (int i = 0; i < 2; i++) {
            int gi = i*256 + tid, row = gi >> 3, col = (gi & 7)*8;
            *(short8*)&sK[0][row][col] =
                *(const short8*)&Kp_r[base + (size_t)(k0+row)*HD + col];
            *(short8*)&sK[1][row][col] =
                *(const short8*)&Kp_i[base + (size_t)(k0+row)*HD + col];
            // V is [d][key] in global: row=d, col=key offset
            *(short8*)&sV[0][row][col] =
                *(const short8*)&Vp_r[base + (size_t)row*NSEQ + k0 + col];
            *(short8*)&sV[1][row][col] =
                *(const short8*)&Vp_i[base + (size_t)row*NSEQ + k0 + col];
        }
        __syncthreads();

        // ---- S = Q conj(K)^T over this 64-key tile ----
        short8 fqr[2], fqi[2], fqrn[2];
        #pragma unroll
        for (int ds = 0; ds < 2; ds++) {
            fqr[ds]  = *(short8*)&sQ[0][wave*16 + l16][ds*32 + quad*8];
            fqi[ds]  = *(short8*)&sQ[1][wave*16 + l16][ds*32 + quad*8];
            fqrn[ds] = *(short8*)&sQ[2][wave*16 + l16][ds*32 + quad*8];
        }
        float4v Sr[4], Si[4];
        #pragma unroll
        for (int t = 0; t < 4; t++) { Sr[t] = zf; Si[t] = zf; }
        #pragma unroll
        for (int t = 0; t < 4; t++)
            #pragma unroll
            for (int ds = 0; ds < 2; ds++) {
                short8 kr = *(short8*)&sK[0][t*16 + l16][ds*32 + quad*8];
                short8 ki = *(short8*)&sK[1][t*16 + l16][ds*32 + quad*8];
                Sr[t] = MFMA16(fqr[ds],  kr, Sr[t]);
                Sr[t] = MFMA16(fqi[ds],  ki, Sr[t]);   // +QiKi (conj)
                Si[t] = MFMA16(fqi[ds],  kr, Si[t]);
                Si[t] = MFMA16(fqrn[ds], ki, Si[t]);   // -QrKi
            }

        // ---- online softmax on |S|/8 ----
        float sc[4][4];
        bool mv[4];
        #pragma unroll
        for (int t = 0; t < 4; t++) {
            mv[t] = smask[k0 + t*16 + l16] != 0;
            #pragma unroll
            for (int r = 0; r < 4; r++) {
                float a = Sr[t][r], c = Si[t][r];
                float s = 0.125f * sqrtf(a*a + c*c);
                sc[t][r] = mv[t] ? s : -1e30f;
            }
        }
        #pragma unroll
        for (int r = 0; r < 4; r++) {
            float mt = fmaxf(fmaxf(sc[0][r], sc[1][r]), fmaxf(sc[2][r], sc[3][r]));
            mt = fmaxf(mt, __shfl_xor(mt, 1, 64));
            mt = fmaxf(mt, __shfl_xor(mt, 2, 64));
            mt = fmaxf(mt, __shfl_xor(mt, 4, 64));
            mt = fmaxf(mt, __shfl_xor(mt, 8, 64));
            float mn = fmaxf(mrow[r], mt);
            float alpha = (mrow[r] > -1e29f) ? __expf(mrow[r] - mn) : 0.f;
            float rs = 0.f;
            #pragma unroll
            for (int t = 0; t < 4; t++) {
                float e = mv[t] ? __expf(sc[t][r] - mn) : 0.f;
                rs += e;
                sP[wave][quad*4 + r][t*16 + l16] = (short)f2b(e);
            }
            rs += __shfl_xor(rs, 1, 64);
            rs += __shfl_xor(rs, 2, 64);
            rs += __shfl_xor(rs, 4, 64);
            rs += __shfl_xor(rs, 8, 64);
            lrow[r] = alpha*lrow[r] + rs;
            mrow[r] = mn;
            #pragma unroll
            for (int t = 0; t < 4; t++) { Or[t][r] *= alpha; Oi[t][r] *= alpha; }
        }

        // ---- O += P @ V (P via LDS C->A layout round-trip) ----
        #pragma unroll
        for (int ks = 0; ks < 2; ks++) {
            short8 fp = *(short8*)&sP[wave][l16][ks*32 + quad*8];
            #pragma unroll
            for (int t = 0; t < 4; t++) {
                short8 vr = *(short8*)&sV[0][t*16 + l16][ks*32 + quad*8];
                short8 vi = *(short8*)&sV[1][t*16 + l16][ks*32 + quad*8];
                Or[t] = MFMA16(fp, vr, Or[t]);
                Oi[t] = MFMA16(fp, vi, Oi[t]);
            }
        }
    }

    // ---- epilogue: O /= l, write attn planes (B*NSEQ, NHD) bf16 ----
    float inv[4];
    #pragma unroll
    for (int r = 0; r < 4; r++) inv[r] = (lrow[r] > 0.f) ? 1.f/lrow[r] : 0.f;
    #pragma unroll
    for (int t = 0; t < 4; t++)
        #pragma unroll
        for (int r = 0; r < 4; r++) {
            int q = qt*64 + wave*16 + quad*4 + r;
            int d = t*16 + l16;
            size_t o = ((size_t)(b*NSEQ + q))*NHD + h*HD + d;
            Ar[o] = (short)f2b(Or[t][r] * inv[r]);
            Ai[o] = (short)f2b(Oi[t][r] * inv[r]);
        }
}

// ---------------------------------------------------------------------------
// Output projection via MFMA: Out = A @ (WOr + i WOi)^T
// A:(4096,NHD) bf16 planes, WO:(RD,NHD) fp32. fp32 planar out (validated R4).
// ---------------------------------------------------------------------------
__global__ __launch_bounds__(256) void cgemm_out(
    const short* __restrict__ A_r, const short* __restrict__ A_i,
    const float* __restrict__ W_r, const float* __restrict__ W_i,
    float* __restrict__ Out, int writeImagPlane)
{
    __shared__ short sA[2][64][72];
    __shared__ short sW[3][64][72];   // Wr, Wi, -Wi
    const int tid  = threadIdx.x;
    const int lane = tid & 63, wave = tid >> 6;
    const int quad = lane >> 4, l16 = lane & 15;
    const int n0 = blockIdx.x * 64, m0 = blockIdx.y * 64;

    float4v zf = {0.f,0.f,0.f,0.f};
    float4v Yr[4], Yi[4];
    #pragma unroll
    for (int t = 0; t < 4; t++) { Yr[t] = zf; Yi[t] = zf; }

    for (int kc = 0; kc < NHD; kc += 64) {
        __syncthreads();
        #pragma unroll
        for (int i = 0; i < 2; i++) {
            int gi = i*256 + tid, row = gi >> 3, col = (gi & 7)*8;
            *(short8*)&sA[0][row][col] =
                *(const short8*)&A_r[(size_t)(m0+row)*NHD + kc + col];
            *(short8*)&sA[1][row][col] =
                *(const short8*)&A_i[(size_t)(m0+row)*NHD + kc + col];
        }
        #pragma unroll
        for (int i = 0; i < 4; i++) {
            int gi = i*256 + tid, row = gi >> 4, col = (gi & 15)*4;
            float4v wr = *(const float4v*)&W_r[(size_t)(n0+row)*NHD + kc + col];
            float4v wi = *(const float4v*)&W_i[(size_t)(n0+row)*NHD + kc + col];
            st4(&sW[0][row][col], wr);
            st4(&sW[1][row][col], wi);
            float4v win = {-wi[0], -wi[1], -wi[2], -wi[3]};
            st4(&sW[2][row][col], win);
        }
        __syncthreads();
        short8 far[2], fai[2];
        #pragma unroll
        for (int ds = 0; ds < 2; ds++) {
            far[ds] = *(short8*)&sA[0][wave*16 + l16][ds*32 + quad*8];
            fai[ds] = *(short8*)&sA[1][wave*16 + l16][ds*32 + quad*8];
        }
        #pragma unroll
        for (int t = 0; t < 4; t++)
            #pragma unroll
            for (int ds = 0; ds < 2; ds++) {
                short8 wr  = *(short8*)&sW[0][t*16 + l16][ds*32 + quad*8];
                short8 wi  = *(short8*)&sW[1][t*16 + l16][ds*32 + quad*8];
                short8 win = *(short8*)&sW[2][t*16 + l16][ds*32 + quad*8];
                Yr[t] = MFMA16(far[ds], wr,  Yr[t]);
                Yr[t] = MFMA16(fai[ds], win, Yr[t]);
                Yi[t] = MFMA16(far[ds], wi,  Yi[t]);
                Yi[t] = MFMA16(fai[ds], wr,  Yi[t]);
            }
    }
    const size_t TOT = (size_t)NBATCH * NSEQ * RD;   // 1,048,576
    #pragma unroll
    for (int t = 0; t < 4; t++)
        #pragma unroll
        for (int r = 0; r < 4; r++) {
            int row = m0 + wave*16 + quad*4 + r;
            int col = n0 + t*16 + l16;
            size_t o = (size_t)row*RD + col;
            Out[o] = Yr[t][r];
            if (writeImagPlane) Out[o + TOT] = Yi[t][r];
        }
}

// ---------------------------------------------------------------------------
extern "C" void kernel_launch(void* const* d_in, const int* in_sizes, int n_in,
                              void* d_out, int out_size, void* d_ws, size_t ws_size,
                              hipStream_t stream)
{
    const float* Qr  = (const float*)d_in[0];
    const float* Qi  = (const float*)d_in[1];
    const float* Kr  = (const float*)d_in[2];
    const float* Ki  = (const float*)d_in[3];
    const float* Vr  = (const float*)d_in[4];
    const float* Vi  = (const float*)d_in[5];
    const float* WQr = (const float*)d_in[6];
    const float* WQi = (const float*)d_in[7];
    const float* WKr = (const float*)d_in[8];
    const float* WKi = (const float*)d_in[9];
    const float* WVr = (const float*)d_in[10];
    const float* WVi = (const float*)d_in[11];
    const float* WOr = (const float*)d_in[12];
    const float* WOi = (const float*)d_in[13];
    float* out = (float*)d_out;

    const size_t P = (size_t)NBATCH * NHEAD * NSEQ * HD;   // 2,097,152 elems
    short* bws = (short*)d_ws;                              // 32 MB planes
    short* Qpr = bws + 0*P;  short* Qpi = bws + 1*P;
    short* Kpr = bws + 2*P;  short* Kpi = bws + 3*P;
    short* Vpr = bws + 4*P;  short* Vpi = bws + 5*P;
    short* Apr = bws + 6*P;  short* Api = bws + 7*P;
    unsigned char* nmask = (unsigned char*)(bws + 8*P);     // 4096 bytes

    const size_t TOT = (size_t)NBATCH * NSEQ * RD;          // 1,048,576
    const int writeImagPlane = ((size_t)out_size >= 2*TOT) ? 1 : 0;

    mask_norm<<<1, 1024, 0, stream>>>(d_in[14], nmask);
    cgemm_proj<<<dim3(8, 64), 256, 0, stream>>>(Qr, Qi, WQr, WQi, Qpr, Qpi, 0);
    cgemm_proj<<<dim3(8, 64), 256, 0, stream>>>(Kr, Ki, WKr, WKi, Kpr, Kpi, 0);
    cgemm_proj<<<dim3(8, 64), 256, 0, stream>>>(Vr, Vi, WVr, WVi, Vpr, Vpi, 1);
    attn_mfma<<<dim3(512), 256, 0, stream>>>(Qpr, Qpi, Kpr, Kpi, Vpr, Vpi,
                                             nmask, Apr, Api);
    cgemm_out<<<dim3(4, 64), 256, 0, stream>>>(Apr, Api, WOr, WOi, out,
                                               writeImagPlane);
}

// Round 6
// 234.230 us; speedup vs baseline: 5.4117x; 1.1691x over previous
//
#include <hip/hip_runtime.h>
#include <math.h>

#define NBATCH 4
#define NSEQ   1024
#define RD     256
#define NHEAD  8
#define HD     64
#define NHD    512   // NHEAD*HD

typedef __attribute__((ext_vector_type(8))) short  short8;
typedef __attribute__((ext_vector_type(4))) short  short4v;
typedef __attribute__((ext_vector_type(4))) float  float4v;

#define MFMA16(a,b,c) __builtin_amdgcn_mfma_f32_16x16x32_bf16(a,b,c,0,0,0)

typedef const void __attribute__((address_space(1)))* gas_t;
typedef void __attribute__((address_space(3)))* las_t;
#define GLOAD16(g, l) __builtin_amdgcn_global_load_lds((gas_t)(g), (las_t)(l), 16, 0, 0)

static __device__ __forceinline__ unsigned short f2b(float f) {
    union { float f; unsigned u; } x; x.f = f;
    unsigned r = x.u + 0x7fffu + ((x.u >> 16) & 1u);   // RNE; inputs finite
    return (unsigned short)(r >> 16);
}
static __device__ __forceinline__ void st4(short* dst, float4v v) {
    short4v p;
    p[0] = (short)f2b(v[0]); p[1] = (short)f2b(v[1]);
    p[2] = (short)f2b(v[2]); p[3] = (short)f2b(v[3]);
    *(short4v*)dst = p;
}

// ---------------------------------------------------------------------------
// Mask normalization (layout-adaptive; validated in R4).
// ---------------------------------------------------------------------------
__global__ __launch_bounds__(1024) void mask_norm(
    const void* __restrict__ mraw, unsigned char* __restrict__ nm)
{
    __shared__ int isByteLayout;
    const int t = threadIdx.x;
    if (t == 0) isByteLayout = 0;
    __syncthreads();
    const int* mi = (const int*)mraw;
    int v = mi[t];
    if (v & ~1) isByteLayout = 1;
    __syncthreads();
    const unsigned char* mb = (const unsigned char*)mraw;
    if (isByteLayout) {
        #pragma unroll
        for (int j = 0; j < 4; j++) { int k = t*4 + j; nm[k] = mb[k] ? 1 : 0; }
    } else {
        #pragma unroll
        for (int j = 0; j < 4; j++) { int k = t*4 + j; nm[k] = mi[k] ? 1 : 0; }
    }
}

// ---------------------------------------------------------------------------
// Merged complex projections via MFMA (z = 0:Q, 1:K, 2:V).
// Y = X @ (Wr + i Wi)^T; X:(4096,RD) fp32 planes, W:(512,RD) fp32.
// z<2: Y[bh][n][d] bf16; z==2: Y[bh][d][n] (V transposed for PV staging).
// ---------------------------------------------------------------------------
struct ProjArgs {
    const float* Xr[3]; const float* Xi[3];
    const float* Wr[3]; const float* Wi[3];
    short* Yr[3]; short* Yi[3];
};

__global__ __launch_bounds__(256) void cgemm_proj(ProjArgs pa)
{
    __shared__ short sX[2][64][72];
    __shared__ short sW[3][64][72];   // Wr, Wi, -Wi
    const int z = blockIdx.z;
    const float* __restrict__ X_r = pa.Xr[z];
    const float* __restrict__ X_i = pa.Xi[z];
    const float* __restrict__ W_r = pa.Wr[z];
    const float* __restrict__ W_i = pa.Wi[z];
    short* __restrict__ Y_r = pa.Yr[z];
    short* __restrict__ Y_i = pa.Yi[z];
    const int transposeOut = (z == 2);

    const int tid  = threadIdx.x;
    const int lane = tid & 63, wave = tid >> 6;
    const int quad = lane >> 4, l16 = lane & 15;
    const int n0 = blockIdx.x * 64, m0 = blockIdx.y * 64;

    float4v zf = {0.f,0.f,0.f,0.f};
    float4v Yr[4], Yi[4];
    #pragma unroll
    for (int t = 0; t < 4; t++) { Yr[t] = zf; Yi[t] = zf; }

    for (int kc = 0; kc < RD; kc += 64) {
        __syncthreads();
        #pragma unroll
        for (int i = 0; i < 4; i++) {
            int gi = i*256 + tid, row = gi >> 4, col = (gi & 15)*4;
            float4v xr = *(const float4v*)&X_r[(size_t)(m0+row)*RD + kc + col];
            float4v xi = *(const float4v*)&X_i[(size_t)(m0+row)*RD + kc + col];
            st4(&sX[0][row][col], xr);
            st4(&sX[1][row][col], xi);
            float4v wr = *(const float4v*)&W_r[(size_t)(n0+row)*RD + kc + col];
            float4v wi = *(const float4v*)&W_i[(size_t)(n0+row)*RD + kc + col];
            st4(&sW[0][row][col], wr);
            st4(&sW[1][row][col], wi);
            float4v win = {-wi[0], -wi[1], -wi[2], -wi[3]};
            st4(&sW[2][row][col], win);
        }
        __syncthreads();
        short8 fxr[2], fxi[2];
        #pragma unroll
        for (int ds = 0; ds < 2; ds++) {
            fxr[ds] = *(short8*)&sX[0][wave*16 + l16][ds*32 + quad*8];
            fxi[ds] = *(short8*)&sX[1][wave*16 + l16][ds*32 + quad*8];
        }
        #pragma unroll
        for (int t = 0; t < 4; t++)
            #pragma unroll
            for (int ds = 0; ds < 2; ds++) {
                short8 wr  = *(short8*)&sW[0][t*16 + l16][ds*32 + quad*8];
                short8 wi  = *(short8*)&sW[1][t*16 + l16][ds*32 + quad*8];
                short8 win = *(short8*)&sW[2][t*16 + l16][ds*32 + quad*8];
                Yr[t] = MFMA16(fxr[ds], wr,  Yr[t]);
                Yr[t] = MFMA16(fxi[ds], win, Yr[t]);
                Yi[t] = MFMA16(fxr[ds], wi,  Yi[t]);
                Yi[t] = MFMA16(fxi[ds], wr,  Yi[t]);
            }
    }
    #pragma unroll
    for (int t = 0; t < 4; t++)
        #pragma unroll
        for (int r = 0; r < 4; r++) {
            int row = m0 + wave*16 + quad*4 + r;   // b*1024+n
            int col = n0 + t*16 + l16;             // h*64+d
            int b = row >> 10, n = row & 1023;
            int h = col >> 6,  d = col & 63;
            size_t o = transposeOut
                ? (((size_t)(b*NHEAD + h))*HD + d)*NSEQ + n
                : (((size_t)(b*NHEAD + h))*NSEQ + n)*HD + d;
            Y_r[o] = (short)f2b(Yr[t][r]);
            Y_i[o] = (short)f2b(Yi[t][r]);
        }
}

// ---------------------------------------------------------------------------
// Flash-style complex attention with MFMA.
// Block = 4 waves, 64 q rows, grid = 32 bh * 16 qtiles = 512.
// Q,K planes [bh][n][d] bf16; V planes [bh][d][n] bf16 (pre-transposed).
// K/V (and initial Q) staged via global_load_lds into UNPADDED 64x64 tiles
// with XOR swizzle (16B unit ^= row&7) -> conflict-free b128 reads, 43KB LDS
// -> 3 blocks/CU. Q fragments live in registers (loop-invariant).
// ---------------------------------------------------------------------------
__global__ __launch_bounds__(256) void attn_mfma(
    const short* __restrict__ Qp_r, const short* __restrict__ Qp_i,
    const short* __restrict__ Kp_r, const short* __restrict__ Kp_i,
    const short* __restrict__ Vp_r, const short* __restrict__ Vp_i,
    const unsigned char* __restrict__ mask,
    short* __restrict__ Ar, short* __restrict__ Ai)
{
    __shared__ short sK[2][64][64];       // [key][d], swizzled
    __shared__ short sV[2][64][64];       // [d][key], swizzled
    __shared__ short sP[4][16][72];       // per-wave P strips (padded, VALU-written)
    __shared__ unsigned char smask[1024];

    const int tid  = threadIdx.x;
    const int lane = tid & 63, wave = tid >> 6;
    const int quad = lane >> 4, l16 = lane & 15;
    const int sw8  = l16 & 7;
    const int qt = blockIdx.x & 15;
    const int bh = blockIdx.x >> 4;
    const int b  = bh >> 3, h = bh & 7;
    const size_t base = (size_t)bh * (NSEQ*HD);

    // staging lane geometry: row-sub = lane>>3, swizzled 16B-unit in row
    const int rsub = lane >> 3;
    const int colg = (lane & 7) ^ rsub;        // global 16B-unit to fetch

    ((int*)smask)[tid] = ((const int*)(mask + b*NSEQ))[tid];

    // ---- stage 64 Q rows into sK space via global_load_lds ----
    {
        const int q0 = qt*64;
        #pragma unroll
        for (int j = 0; j < 4; j++) {
            int c = wave*4 + j;                 // 16 chunks: plane=c>>3, jj=c&7
            const short* gp = (c >> 3) ? Qp_i : Qp_r;
            short* lp = (c >> 3) ? &sK[1][0][0] : &sK[0][0][0];
            int jj = c & 7;
            int row = jj*8 + rsub;
            GLOAD16(gp + base + (size_t)(q0 + row)*HD + colg*8, lp + jj*512);
        }
    }
    __syncthreads();

    // ---- Q fragments -> registers (loop-invariant) ----
    short8 fqr[2], fqi[2], fqrn[2];
    {
        const short nk = (short)0x8000;
        short8 neg = {nk,nk,nk,nk,nk,nk,nk,nk};
        const int qrow = wave*16 + l16;
        #pragma unroll
        for (int ds = 0; ds < 2; ds++) {
            int u = ((ds*4 + quad) ^ sw8) * 8;
            fqr[ds]  = *(short8*)&sK[0][qrow][u];
            fqi[ds]  = *(short8*)&sK[1][qrow][u];
            fqrn[ds] = fqr[ds] ^ neg;
        }
    }

    float4v zf = {0.f,0.f,0.f,0.f};
    float4v Or[4], Oi[4];
    float mrow[4], lrow[4];
    #pragma unroll
    for (int t = 0; t < 4; t++) { Or[t] = zf; Oi[t] = zf; }
    #pragma unroll
    for (int r = 0; r < 4; r++) { mrow[r] = -1e30f; lrow[r] = 0.f; }

    for (int kt = 0; kt < 16; kt++) {
        const int k0 = kt*64;
        __syncthreads();      // prev tile fully consumed
        {
            // wave -> one plane: 0:Kr 1:Ki 2:Vr 3:Vi; 8 chunks of 1024B each
            const short* gp; short* lp; int isV;
            if      (wave == 0) { gp = Kp_r; lp = &sK[0][0][0]; isV = 0; }
            else if (wave == 1) { gp = Kp_i; lp = &sK[1][0][0]; isV = 0; }
            else if (wave == 2) { gp = Vp_r; lp = &sV[0][0][0]; isV = 1; }
            else                { gp = Vp_i; lp = &sV[1][0][0]; isV = 1; }
            #pragma unroll
            for (int j = 0; j < 8; j++) {
                int row = j*8 + rsub;
                const short* g = isV
                    ? gp + base + (size_t)row*NSEQ + k0 + colg*8
                    : gp + base + (size_t)(k0 + row)*HD + colg*8;
                GLOAD16(g, lp + j*512);
            }
        }
        __syncthreads();      // vmcnt drained by compiler before barrier

        // ---- S = Q conj(K)^T over this 64-key tile ----
        float4v Sr[4], Si[4];
        #pragma unroll
        for (int t = 0; t < 4; t++) { Sr[t] = zf; Si[t] = zf; }
        #pragma unroll
        for (int t = 0; t < 4; t++)
            #pragma unroll
            for (int ds = 0; ds < 2; ds++) {
                int u = ((ds*4 + quad) ^ sw8) * 8;
                short8 kr = *(short8*)&sK[0][t*16 + l16][u];
                short8 ki = *(short8*)&sK[1][t*16 + l16][u];
                Sr[t] = MFMA16(fqr[ds],  kr, Sr[t]);
                Sr[t] = MFMA16(fqi[ds],  ki, Sr[t]);   // +QiKi (conj)
                Si[t] = MFMA16(fqi[ds],  kr, Si[t]);
                Si[t] = MFMA16(fqrn[ds], ki, Si[t]);   // -QrKi
            }

        // ---- online softmax on |S|/8 ----
        float sc[4][4];
        bool mv[4];
        #pragma unroll
        for (int t = 0; t < 4; t++) {
            mv[t] = smask[k0 + t*16 + l16] != 0;
            #pragma unroll
            for (int r = 0; r < 4; r++) {
                float a = Sr[t][r], c = Si[t][r];
                float s = 0.125f * sqrtf(a*a + c*c);
                sc[t][r] = mv[t] ? s : -1e30f;
            }
        }
        #pragma unroll
        for (int r = 0; r < 4; r++) {
            float mt = fmaxf(fmaxf(sc[0][r], sc[1][r]), fmaxf(sc[2][r], sc[3][r]));
            mt = fmaxf(mt, __shfl_xor(mt, 1, 64));
            mt = fmaxf(mt, __shfl_xor(mt, 2, 64));
            mt = fmaxf(mt, __shfl_xor(mt, 4, 64));
            mt = fmaxf(mt, __shfl_xor(mt, 8, 64));
            float mn = fmaxf(mrow[r], mt);
            float alpha = (mrow[r] > -1e29f) ? __expf(mrow[r] - mn) : 0.f;
            float rs = 0.f;
            #pragma unroll
            for (int t = 0; t < 4; t++) {
                float e = mv[t] ? __expf(sc[t][r] - mn) : 0.f;
                rs += e;
                sP[wave][quad*4 + r][t*16 + l16] = (short)f2b(e);
            }
            rs += __shfl_xor(rs, 1, 64);
            rs += __shfl_xor(rs, 2, 64);
            rs += __shfl_xor(rs, 4, 64);
            rs += __shfl_xor(rs, 8, 64);
            lrow[r] = alpha*lrow[r] + rs;
            mrow[r] = mn;
            #pragma unroll
            for (int t = 0; t < 4; t++) { Or[t][r] *= alpha; Oi[t][r] *= alpha; }
        }

        // ---- O += P @ V ----
        #pragma unroll
        for (int ks = 0; ks < 2; ks++) {
            short8 fp = *(short8*)&sP[wave][l16][ks*32 + quad*8];
            #pragma unroll
            for (int t = 0; t < 4; t++) {
                int u = ((ks*4 + quad) ^ sw8) * 8;
                short8 vr = *(short8*)&sV[0][t*16 + l16][u];
                short8 vi = *(short8*)&sV[1][t*16 + l16][u];
                Or[t] = MFMA16(fp, vr, Or[t]);
                Oi[t] = MFMA16(fp, vi, Oi[t]);
            }
        }
    }

    // ---- epilogue: O /= l, write attn planes (B*NSEQ, NHD) bf16 ----
    float inv[4];
    #pragma unroll
    for (int r = 0; r < 4; r++) inv[r] = (lrow[r] > 0.f) ? 1.f/lrow[r] : 0.f;
    #pragma unroll
    for (int t = 0; t < 4; t++)
        #pragma unroll
        for (int r = 0; r < 4; r++) {
            int q = qt*64 + wave*16 + quad*4 + r;
            int d = t*16 + l16;
            size_t o = ((size_t)(b*NSEQ + q))*NHD + h*HD + d;
            Ar[o] = (short)f2b(Or[t][r] * inv[r]);
            Ai[o] = (short)f2b(Oi[t][r] * inv[r]);
        }
}

// ---------------------------------------------------------------------------
// Output projection via MFMA: Out = A @ (WOr + i WOi)^T
// A:(4096,NHD) bf16 planes, WO:(RD,NHD) fp32. fp32 planar out (validated R4).
// ---------------------------------------------------------------------------
__global__ __launch_bounds__(256) void cgemm_out(
    const short* __restrict__ A_r, const short* __restrict__ A_i,
    const float* __restrict__ W_r, const float* __restrict__ W_i,
    float* __restrict__ Out, int writeImagPlane)
{
    __shared__ short sA[2][64][72];
    __shared__ short sW[3][64][72];   // Wr, Wi, -Wi
    const int tid  = threadIdx.x;
    const int lane = tid & 63, wave = tid >> 6;
    const int quad = lane >> 4, l16 = lane & 15;
    const int n0 = blockIdx.x * 64, m0 = blockIdx.y * 64;

    float4v zf = {0.f,0.f,0.f,0.f};
    float4v Yr[4], Yi[4];
    #pragma unroll
    for (int t = 0; t < 4; t++) { Yr[t] = zf; Yi[t] = zf; }

    for (int kc = 0; kc < NHD; kc += 64) {
        __syncthreads();
        #pragma unroll
        for (int i = 0; i < 2; i++) {
            int gi = i*256 + tid, row = gi >> 3, col = (gi & 7)*8;
            *(short8*)&sA[0][row][col] =
                *(const short8*)&A_r[(size_t)(m0+row)*NHD + kc + col];
            *(short8*)&sA[1][row][col] =
                *(const short8*)&A_i[(size_t)(m0+row)*NHD + kc + col];
        }
        #pragma unroll
        for (int i = 0; i < 4; i++) {
            int gi = i*256 + tid, row = gi >> 4, col = (gi & 15)*4;
            float4v wr = *(const float4v*)&W_r[(size_t)(n0+row)*NHD + kc + col];
            float4v wi = *(const float4v*)&W_i[(size_t)(n0+row)*NHD + kc + col];
            st4(&sW[0][row][col], wr);
            st4(&sW[1][row][col], wi);
            float4v win = {-wi[0], -wi[1], -wi[2], -wi[3]};
            st4(&sW[2][row][col], win);
        }
        __syncthreads();
        short8 far[2], fai[2];
        #pragma unroll
        for (int ds = 0; ds < 2; ds++) {
            far[ds] = *(short8*)&sA[0][wave*16 + l16][ds*32 + quad*8];
            fai[ds] = *(short8*)&sA[1][wave*16 + l16][ds*32 + quad*8];
        }
        #pragma unroll
        for (int t = 0; t < 4; t++)
            #pragma unroll
            for (int ds = 0; ds < 2; ds++) {
                short8 wr  = *(short8*)&sW[0][t*16 + l16][ds*32 + quad*8];
                short8 wi  = *(short8*)&sW[1][t*16 + l16][ds*32 + quad*8];
                short8 win = *(short8*)&sW[2][t*16 + l16][ds*32 + quad*8];
                Yr[t] = MFMA16(far[ds], wr,  Yr[t]);
                Yr[t] = MFMA16(fai[ds], win, Yr[t]);
                Yi[t] = MFMA16(far[ds], wi,  Yi[t]);
                Yi[t] = MFMA16(fai[ds], wr,  Yi[t]);
            }
    }
    const size_t TOT = (size_t)NBATCH * NSEQ * RD;   // 1,048,576
    #pragma unroll
    for (int t = 0; t < 4; t++)
        #pragma unroll
        for (int r = 0; r < 4; r++) {
            int row = m0 + wave*16 + quad*4 + r;
            int col = n0 + t*16 + l16;
            size_t o = (size_t)row*RD + col;
            Out[o] = Yr[t][r];
            if (writeImagPlane) Out[o + TOT] = Yi[t][r];
        }
}

// ---------------------------------------------------------------------------
extern "C" void kernel_launch(void* const* d_in, const int* in_sizes, int n_in,
                              void* d_out, int out_size, void* d_ws, size_t ws_size,
                              hipStream_t stream)
{
    const float* WOr = (const float*)d_in[12];
    const float* WOi = (const float*)d_in[13];
    float* out = (float*)d_out;

    const size_t P = (size_t)NBATCH * NHEAD * NSEQ * HD;   // 2,097,152 elems
    short* bws = (short*)d_ws;                              // 32 MB planes
    short* Qpr = bws + 0*P;  short* Qpi = bws + 1*P;
    short* Kpr = bws + 2*P;  short* Kpi = bws + 3*P;
    short* Vpr = bws + 4*P;  short* Vpi = bws + 5*P;
    short* Apr = bws + 6*P;  short* Api = bws + 7*P;
    unsigned char* nmask = (unsigned char*)(bws + 8*P);     // 4096 bytes

    const size_t TOT = (size_t)NBATCH * NSEQ * RD;          // 1,048,576
    const int writeImagPlane = ((size_t)out_size >= 2*TOT) ? 1 : 0;

    ProjArgs pa;
    pa.Xr[0] = (const float*)d_in[0];  pa.Xi[0] = (const float*)d_in[1];
    pa.Xr[1] = (const float*)d_in[2];  pa.Xi[1] = (const float*)d_in[3];
    pa.Xr[2] = (const float*)d_in[4];  pa.Xi[2] = (const float*)d_in[5];
    pa.Wr[0] = (const float*)d_in[6];  pa.Wi[0] = (const float*)d_in[7];
    pa.Wr[1] = (const float*)d_in[8];  pa.Wi[1] = (const float*)d_in[9];
    pa.Wr[2] = (const float*)d_in[10]; pa.Wi[2] = (const float*)d_in[11];
    pa.Yr[0] = Qpr; pa.Yi[0] = Qpi;
    pa.Yr[1] = Kpr; pa.Yi[1] = Kpi;
    pa.Yr[2] = Vpr; pa.Yi[2] = Vpi;

    mask_norm<<<1, 1024, 0, stream>>>(d_in[14], nmask);
    cgemm_proj<<<dim3(8, 64, 3), 256, 0, stream>>>(pa);
    attn_mfma<<<dim3(512), 256, 0, stream>>>(Qpr, Qpi, Kpr, Kpi, Vpr, Vpi,
                                             nmask, Apr, Api);
    cgemm_out<<<dim3(4, 64), 256, 0, stream>>>(Apr, Api, WOr, WOi, out,
                                               writeImagPlane);
}

// Round 7
// 191.736 us; speedup vs baseline: 6.6110x; 1.2216x over previous
//
#include <hip/hip_runtime.h>
#include <math.h>

#define NBATCH 4
#define NSEQ   1024
#define RD     256
#define NHEAD  8
#define HD     64
#define NHD    512   // NHEAD*HD

typedef __attribute__((ext_vector_type(8))) short  short8;
typedef __attribute__((ext_vector_type(4))) short  short4v;
typedef __attribute__((ext_vector_type(4))) float  float4v;

#define MFMA16(a,b,c) __builtin_amdgcn_mfma_f32_16x16x32_bf16(a,b,c,0,0,0)

typedef const void __attribute__((address_space(1)))* gas_t;
typedef void __attribute__((address_space(3)))* las_t;
#define GLOAD16(g, l) __builtin_amdgcn_global_load_lds((gas_t)(g), (las_t)(l), 16, 0, 0)

static __device__ __forceinline__ unsigned short f2b(float f) {
    union { float f; unsigned u; } x; x.f = f;
    unsigned r = x.u + 0x7fffu + ((x.u >> 16) & 1u);   // RNE; inputs finite
    return (unsigned short)(r >> 16);
}
static __device__ __forceinline__ void st4(short* dst, float4v v) {
    short4v p;
    p[0] = (short)f2b(v[0]); p[1] = (short)f2b(v[1]);
    p[2] = (short)f2b(v[2]); p[3] = (short)f2b(v[3]);
    *(short4v*)dst = p;
}

// ---------------------------------------------------------------------------
// Mask normalization (layout-adaptive; validated in R4).
// ---------------------------------------------------------------------------
__global__ __launch_bounds__(1024) void mask_norm(
    const void* __restrict__ mraw, unsigned char* __restrict__ nm)
{
    __shared__ int isByteLayout;
    const int t = threadIdx.x;
    if (t == 0) isByteLayout = 0;
    __syncthreads();
    const int* mi = (const int*)mraw;
    int v = mi[t];
    if (v & ~1) isByteLayout = 1;
    __syncthreads();
    const unsigned char* mb = (const unsigned char*)mraw;
    if (isByteLayout) {
        #pragma unroll
        for (int j = 0; j < 4; j++) { int k = t*4 + j; nm[k] = mb[k] ? 1 : 0; }
    } else {
        #pragma unroll
        for (int j = 0; j < 4; j++) { int k = t*4 + j; nm[k] = mi[k] ? 1 : 0; }
    }
}

// ---------------------------------------------------------------------------
// Bulk fp32 -> bf16 conversion of all inputs (one launch, y = array id).
// ---------------------------------------------------------------------------
struct ConvArgs { const float* src[14]; short* dst[14]; int n4[14]; };

__global__ __launch_bounds__(256) void convert_bf16(ConvArgs ca)
{
    const int a = blockIdx.y;
    const float* __restrict__ s = ca.src[a];
    short* __restrict__ d = ca.dst[a];
    const int n4 = ca.n4[a];
    for (int i = blockIdx.x*256 + threadIdx.x; i < n4; i += gridDim.x*256) {
        float4v v = *(const float4v*)(s + (size_t)i*4);
        st4(d + (size_t)i*4, v);
    }
}

// ---------------------------------------------------------------------------
// Zero d_out (atomic accumulation target for cgemm_out).
// ---------------------------------------------------------------------------
__global__ __launch_bounds__(256) void zero_out(float* __restrict__ out, int n4)
{
    float4v z = {0.f,0.f,0.f,0.f};
    for (int i = blockIdx.x*256 + threadIdx.x; i < n4; i += gridDim.x*256)
        *(float4v*)(out + (size_t)i*4) = z;
}

// ---------------------------------------------------------------------------
// Merged complex projections, all-bf16, GLOAD16 staging (z = 0:Q, 1:K, 2:V).
// Y = X @ (Wr + i Wi)^T; X:(4096,RD) bf16 planes, W:(512,RD) bf16 planes.
// z<2: Y[bh][n][d]; z==2: Y[bh][d][n] (V transposed for PV staging).
// LDS 32KB -> 5 blocks/CU. Negation of Xi done in registers (no -Wi plane).
// ---------------------------------------------------------------------------
struct ProjArgs {
    const short* Xr[3]; const short* Xi[3];
    const short* Wr[3]; const short* Wi[3];
    short* Yr[3]; short* Yi[3];
};

__global__ __launch_bounds__(256) void cgemm_proj(ProjArgs pa)
{
    __shared__ short sX[2][64][64];
    __shared__ short sW[2][64][64];
    const int z = blockIdx.z;
    const short* __restrict__ X_r = pa.Xr[z];
    const short* __restrict__ X_i = pa.Xi[z];
    const short* __restrict__ W_r = pa.Wr[z];
    const short* __restrict__ W_i = pa.Wi[z];
    short* __restrict__ Y_r = pa.Yr[z];
    short* __restrict__ Y_i = pa.Yi[z];
    const int transposeOut = (z == 2);

    const int tid  = threadIdx.x;
    const int lane = tid & 63, wave = tid >> 6;
    const int quad = lane >> 4, l16 = lane & 15;
    const int sw8  = l16 & 7;
    const int rsub = lane >> 3;
    const int colg = (lane & 7) ^ rsub;
    const int n0 = blockIdx.x * 64, m0 = blockIdx.y * 64;

    const short nk = (short)0x8000;
    const short8 neg = {nk,nk,nk,nk,nk,nk,nk,nk};

    float4v zf = {0.f,0.f,0.f,0.f};
    float4v Yr[4], Yi[4];
    #pragma unroll
    for (int t = 0; t < 4; t++) { Yr[t] = zf; Yi[t] = zf; }

    for (int kc = 0; kc < RD; kc += 64) {
        __syncthreads();
        {
            const short* gp; short* lp; int rbase;
            if      (wave == 0) { gp = X_r; lp = &sX[0][0][0]; rbase = m0; }
            else if (wave == 1) { gp = X_i; lp = &sX[1][0][0]; rbase = m0; }
            else if (wave == 2) { gp = W_r; lp = &sW[0][0][0]; rbase = n0; }
            else                { gp = W_i; lp = &sW[1][0][0]; rbase = n0; }
            #pragma unroll
            for (int j = 0; j < 8; j++) {
                int row = j*8 + rsub;
                GLOAD16(gp + (size_t)(rbase + row)*RD + kc + colg*8, lp + j*512);
            }
        }
        __syncthreads();
        short8 fxr[2], fxi[2], fxin[2];
        #pragma unroll
        for (int ds = 0; ds < 2; ds++) {
            int u = ((ds*4 + quad) ^ sw8) * 8;
            fxr[ds]  = *(short8*)&sX[0][wave*16 + l16][u];
            fxi[ds]  = *(short8*)&sX[1][wave*16 + l16][u];
            fxin[ds] = fxi[ds] ^ neg;
        }
        #pragma unroll
        for (int t = 0; t < 4; t++)
            #pragma unroll
            for (int ds = 0; ds < 2; ds++) {
                int u = ((ds*4 + quad) ^ sw8) * 8;
                short8 wr = *(short8*)&sW[0][t*16 + l16][u];
                short8 wi = *(short8*)&sW[1][t*16 + l16][u];
                Yr[t] = MFMA16(fxr[ds],  wr, Yr[t]);
                Yr[t] = MFMA16(fxin[ds], wi, Yr[t]);   // -Xi*Wi
                Yi[t] = MFMA16(fxr[ds],  wi, Yi[t]);
                Yi[t] = MFMA16(fxi[ds],  wr, Yi[t]);
            }
    }
    #pragma unroll
    for (int t = 0; t < 4; t++)
        #pragma unroll
        for (int r = 0; r < 4; r++) {
            int row = m0 + wave*16 + quad*4 + r;   // b*1024+n
            int col = n0 + t*16 + l16;             // h*64+d
            int b = row >> 10, n = row & 1023;
            int h = col >> 6,  d = col & 63;
            size_t o = transposeOut
                ? (((size_t)(b*NHEAD + h))*HD + d)*NSEQ + n
                : (((size_t)(b*NHEAD + h))*NSEQ + n)*HD + d;
            Y_r[o] = (short)f2b(Yr[t][r]);
            Y_i[o] = (short)f2b(Yi[t][r]);
        }
}

// ---------------------------------------------------------------------------
// Flash-style complex attention with MFMA — no-max softmax.
// Scores = |S|/8 >= 0 and bounded (<~2), so exp() needs no max shift; the
// online max/rescale machinery is deleted. Per-lane l partials, one epilogue
// reduction. Block = 4 waves, 64 q rows, grid = 512.
// ---------------------------------------------------------------------------
__global__ __launch_bounds__(256) void attn_mfma(
    const short* __restrict__ Qp_r, const short* __restrict__ Qp_i,
    const short* __restrict__ Kp_r, const short* __restrict__ Kp_i,
    const short* __restrict__ Vp_r, const short* __restrict__ Vp_i,
    const unsigned char* __restrict__ mask,
    short* __restrict__ Ar, short* __restrict__ Ai)
{
    __shared__ short sK[2][64][64];       // [key][d], swizzled
    __shared__ short sV[2][64][64];       // [d][key], swizzled
    __shared__ short sP[4][16][72];       // per-wave P strips (padded)
    __shared__ unsigned char smask[1024];

    const int tid  = threadIdx.x;
    const int lane = tid & 63, wave = tid >> 6;
    const int quad = lane >> 4, l16 = lane & 15;
    const int sw8  = l16 & 7;
    const int qt = blockIdx.x & 15;
    const int bh = blockIdx.x >> 4;
    const int b  = bh >> 3, h = bh & 7;
    const size_t base = (size_t)bh * (NSEQ*HD);

    const int rsub = lane >> 3;
    const int colg = (lane & 7) ^ rsub;

    ((int*)smask)[tid] = ((const int*)(mask + b*NSEQ))[tid];

    // ---- stage 64 Q rows into sK space via global_load_lds ----
    {
        const int q0 = qt*64;
        #pragma unroll
        for (int j = 0; j < 4; j++) {
            int c = wave*4 + j;
            const short* gp = (c >> 3) ? Qp_i : Qp_r;
            short* lp = (c >> 3) ? &sK[1][0][0] : &sK[0][0][0];
            int jj = c & 7;
            int row = jj*8 + rsub;
            GLOAD16(gp + base + (size_t)(q0 + row)*HD + colg*8, lp + jj*512);
        }
    }
    __syncthreads();

    // ---- Q fragments -> registers (loop-invariant) ----
    short8 fqr[2], fqi[2], fqrn[2];
    {
        const short nk = (short)0x8000;
        short8 neg = {nk,nk,nk,nk,nk,nk,nk,nk};
        const int qrow = wave*16 + l16;
        #pragma unroll
        for (int ds = 0; ds < 2; ds++) {
            int u = ((ds*4 + quad) ^ sw8) * 8;
            fqr[ds]  = *(short8*)&sK[0][qrow][u];
            fqi[ds]  = *(short8*)&sK[1][qrow][u];
            fqrn[ds] = fqr[ds] ^ neg;
        }
    }

    float4v zf = {0.f,0.f,0.f,0.f};
    float4v Or[4], Oi[4];
    float lrow[4];
    #pragma unroll
    for (int t = 0; t < 4; t++) { Or[t] = zf; Oi[t] = zf; }
    #pragma unroll
    for (int r = 0; r < 4; r++) lrow[r] = 0.f;

    const float C2 = 0.18033688f;   // 0.125 * log2(e)

    for (int kt = 0; kt < 16; kt++) {
        const int k0 = kt*64;
        __syncthreads();
        {
            const short* gp; short* lp; int isV;
            if      (wave == 0) { gp = Kp_r; lp = &sK[0][0][0]; isV = 0; }
            else if (wave == 1) { gp = Kp_i; lp = &sK[1][0][0]; isV = 0; }
            else if (wave == 2) { gp = Vp_r; lp = &sV[0][0][0]; isV = 1; }
            else                { gp = Vp_i; lp = &sV[1][0][0]; isV = 1; }
            #pragma unroll
            for (int j = 0; j < 8; j++) {
                int row = j*8 + rsub;
                const short* g = isV
                    ? gp + base + (size_t)row*NSEQ + k0 + colg*8
                    : gp + base + (size_t)(k0 + row)*HD + colg*8;
                GLOAD16(g, lp + j*512);
            }
        }
        __syncthreads();

        // ---- S = Q conj(K)^T ----
        float4v Sr[4], Si[4];
        #pragma unroll
        for (int t = 0; t < 4; t++) { Sr[t] = zf; Si[t] = zf; }
        #pragma unroll
        for (int t = 0; t < 4; t++)
            #pragma unroll
            for (int ds = 0; ds < 2; ds++) {
                int u = ((ds*4 + quad) ^ sw8) * 8;
                short8 kr = *(short8*)&sK[0][t*16 + l16][u];
                short8 ki = *(short8*)&sK[1][t*16 + l16][u];
                Sr[t] = MFMA16(fqr[ds],  kr, Sr[t]);
                Sr[t] = MFMA16(fqi[ds],  ki, Sr[t]);
                Si[t] = MFMA16(fqi[ds],  kr, Si[t]);
                Si[t] = MFMA16(fqrn[ds], ki, Si[t]);
            }

        // ---- e = exp(|S|/8) (no max shift), accumulate per-lane l ----
        #pragma unroll
        for (int t = 0; t < 4; t++) {
            bool mv = smask[k0 + t*16 + l16] != 0;
            #pragma unroll
            for (int r = 0; r < 4; r++) {
                float a = Sr[t][r], c = Si[t][r];
                float x = fmaf(a, a, c*c);
                float s = x * __builtin_amdgcn_rsqf(x + 1e-30f);  // ~= sqrt(x)
                float e = mv ? exp2f(C2 * s) : 0.f;
                lrow[r] += e;
                sP[wave][quad*4 + r][t*16 + l16] = (short)f2b(e);
            }
        }

        // ---- O += P @ V ----
        #pragma unroll
        for (int ks = 0; ks < 2; ks++) {
            short8 fp = *(short8*)&sP[wave][l16][ks*32 + quad*8];
            #pragma unroll
            for (int t = 0; t < 4; t++) {
                int u = ((ks*4 + quad) ^ sw8) * 8;
                short8 vr = *(short8*)&sV[0][t*16 + l16][u];
                short8 vi = *(short8*)&sV[1][t*16 + l16][u];
                Or[t] = MFMA16(fp, vr, Or[t]);
                Oi[t] = MFMA16(fp, vi, Oi[t]);
            }
        }
    }

    // ---- epilogue: reduce l across 16-lane row groups, O /= l, write bf16 ----
    float inv[4];
    #pragma unroll
    for (int r = 0; r < 4; r++) {
        float ls = lrow[r];
        ls += __shfl_xor(ls, 1, 64);
        ls += __shfl_xor(ls, 2, 64);
        ls += __shfl_xor(ls, 4, 64);
        ls += __shfl_xor(ls, 8, 64);
        inv[r] = (ls > 0.f) ? 1.f/ls : 0.f;
    }
    #pragma unroll
    for (int t = 0; t < 4; t++)
        #pragma unroll
        for (int r = 0; r < 4; r++) {
            int q = qt*64 + wave*16 + quad*4 + r;
            int d = t*16 + l16;
            size_t o = ((size_t)(b*NSEQ + q))*NHD + h*HD + d;
            Ar[o] = (short)f2b(Or[t][r] * inv[r]);
            Ai[o] = (short)f2b(Oi[t][r] * inv[r]);
        }
}

// ---------------------------------------------------------------------------
// Output projection, all-bf16, GLOAD16 staging, split-K2, atomic fp32 out.
// Out = A @ (WOr + i WOi)^T; A:(4096,NHD) bf16, WO:(RD,NHD) bf16.
// ---------------------------------------------------------------------------
__global__ __launch_bounds__(256) void cgemm_out(
    const short* __restrict__ A_r, const short* __restrict__ A_i,
    const short* __restrict__ W_r, const short* __restrict__ W_i,
    float* __restrict__ Out, int writeImagPlane)
{
    __shared__ short sA[2][64][64];
    __shared__ short sW[2][64][64];
    const int tid  = threadIdx.x;
    const int lane = tid & 63, wave = tid >> 6;
    const int quad = lane >> 4, l16 = lane & 15;
    const int sw8  = l16 & 15 & 7;
    const int rsub = lane >> 3;
    const int colg = (lane & 7) ^ rsub;
    const int n0 = blockIdx.x * 64, m0 = blockIdx.y * 64;
    const int z  = blockIdx.z;                    // K half

    const short nk = (short)0x8000;
    const short8 neg = {nk,nk,nk,nk,nk,nk,nk,nk};

    float4v zf = {0.f,0.f,0.f,0.f};
    float4v Yr[4], Yi[4];
    #pragma unroll
    for (int t = 0; t < 4; t++) { Yr[t] = zf; Yi[t] = zf; }

    for (int kc = z*256; kc < z*256 + 256; kc += 64) {
        __syncthreads();
        {
            const short* gp; short* lp; int rbase;
            if      (wave == 0) { gp = A_r; lp = &sA[0][0][0]; rbase = m0; }
            else if (wave == 1) { gp = A_i; lp = &sA[1][0][0]; rbase = m0; }
            else if (wave == 2) { gp = W_r; lp = &sW[0][0][0]; rbase = n0; }
            else                { gp = W_i; lp = &sW[1][0][0]; rbase = n0; }
            #pragma unroll
            for (int j = 0; j < 8; j++) {
                int row = j*8 + rsub;
                GLOAD16(gp + (size_t)(rbase + row)*NHD + kc + colg*8, lp + j*512);
            }
        }
        __syncthreads();
        short8 far[2], fai[2], fain[2];
        #pragma unroll
        for (int ds = 0; ds < 2; ds++) {
            int u = ((ds*4 + quad) ^ sw8) * 8;
            far[ds]  = *(short8*)&sA[0][wave*16 + l16][u];
            fai[ds]  = *(short8*)&sA[1][wave*16 + l16][u];
            fain[ds] = fai[ds] ^ neg;
        }
        #pragma unroll
        for (int t = 0; t < 4; t++)
            #pragma unroll
            for (int ds = 0; ds < 2; ds++) {
                int u = ((ds*4 + quad) ^ sw8) * 8;
                short8 wr = *(short8*)&sW[0][t*16 + l16][u];
                short8 wi = *(short8*)&sW[1][t*16 + l16][u];
                Yr[t] = MFMA16(far[ds],  wr, Yr[t]);
                Yr[t] = MFMA16(fain[ds], wi, Yr[t]);
                Yi[t] = MFMA16(far[ds],  wi, Yi[t]);
                Yi[t] = MFMA16(fai[ds],  wr, Yi[t]);
            }
    }
    const size_t TOT = (size_t)NBATCH * NSEQ * RD;   // 1,048,576
    #pragma unroll
    for (int t = 0; t < 4; t++)
        #pragma unroll
        for (int r = 0; r < 4; r++) {
            int row = m0 + wave*16 + quad*4 + r;
            int col = n0 + t*16 + l16;
            size_t o = (size_t)row*RD + col;
            atomicAdd(&Out[o], Yr[t][r]);
            if (writeImagPlane) atomicAdd(&Out[o + TOT], Yi[t][r]);
        }
}

// ---------------------------------------------------------------------------
extern "C" void kernel_launch(void* const* d_in, const int* in_sizes, int n_in,
                              void* d_out, int out_size, void* d_ws, size_t ws_size,
                              hipStream_t stream)
{
    float* out = (float*)d_out;

    const size_t P = (size_t)NBATCH * NHEAD * NSEQ * HD;   // 2,097,152
    const size_t H = (size_t)NBATCH * NSEQ * RD;           // 1,048,576
    const size_t WSZ = (size_t)NHD * RD;                   // 131,072

    short* bws = (short*)d_ws;
    // bf16 projected planes [0, 24MB)
    short* Qpr = bws + 0*P;  short* Qpi = bws + 1*P;
    short* Kpr = bws + 2*P;  short* Kpi = bws + 3*P;
    short* Vpr = bws + 4*P;  short* Vpi = bws + 5*P;
    // converted-input region @ 24MB (dead after cgemm_proj, except WO)
    short* conv = bws + 6*P;
    short* cX[6]; for (int i = 0; i < 6; i++) cX[i] = conv + i*H;       // 12MB
    short* cW[6]; for (int i = 0; i < 6; i++) cW[i] = conv + 6*H + i*WSZ;
    short* cWOr = conv + 6*H + 6*WSZ;
    short* cWOi = conv + 6*H + 7*WSZ;
    // A planes alias the (dead) converted X region
    short* Apr = conv;          // 4MB
    short* Api = conv + P;      // 4MB
    unsigned char* nmask = (unsigned char*)(conv + 6*H + 8*WSZ);  // 4KB

    const size_t TOT = (size_t)NBATCH * NSEQ * RD;
    const int writeImagPlane = ((size_t)out_size >= 2*TOT) ? 1 : 0;

    ConvArgs ca;
    for (int i = 0; i < 6; i++) {               // Q/K/V planes
        ca.src[i] = (const float*)d_in[i];  ca.dst[i] = cX[i];  ca.n4[i] = (int)(H/4);
    }
    for (int i = 0; i < 6; i++) {               // WQ/WK/WV
        ca.src[6+i] = (const float*)d_in[6+i]; ca.dst[6+i] = cW[i]; ca.n4[6+i] = (int)(WSZ/4);
    }
    ca.src[12] = (const float*)d_in[12]; ca.dst[12] = cWOr; ca.n4[12] = (int)(WSZ/4);
    ca.src[13] = (const float*)d_in[13]; ca.dst[13] = cWOi; ca.n4[13] = (int)(WSZ/4);

    ProjArgs pa;
    pa.Xr[0] = cX[0]; pa.Xi[0] = cX[1];
    pa.Xr[1] = cX[2]; pa.Xi[1] = cX[3];
    pa.Xr[2] = cX[4]; pa.Xi[2] = cX[5];
    pa.Wr[0] = cW[0]; pa.Wi[0] = cW[1];
    pa.Wr[1] = cW[2]; pa.Wi[1] = cW[3];
    pa.Wr[2] = cW[4]; pa.Wi[2] = cW[5];
    pa.Yr[0] = Qpr; pa.Yi[0] = Qpi;
    pa.Yr[1] = Kpr; pa.Yi[1] = Kpi;
    pa.Yr[2] = Vpr; pa.Yi[2] = Vpi;

    mask_norm<<<1, 1024, 0, stream>>>(d_in[14], nmask);
    convert_bf16<<<dim3(256, 14), 256, 0, stream>>>(ca);
    cgemm_proj<<<dim3(8, 64, 3), 256, 0, stream>>>(pa);
    attn_mfma<<<dim3(512), 256, 0, stream>>>(Qpr, Qpi, Kpr, Kpi, Vpr, Vpi,
                                             nmask, Apr, Api);
    zero_out<<<dim3(512), 256, 0, stream>>>(out, out_size/4);
    cgemm_out<<<dim3(4, 64, 2), 256, 0, stream>>>(Apr, Api, cWOr, cWOi, out,
                                                  writeImagPlane);
}